// Round 4
// baseline (251.520 us; speedup 1.0000x reference)
//
#include <hip/hip_runtime.h>

// BEV transformer block, MI355X/gfx950.  Round 4.
// ws layout (bytes) — regions aliased across kernel lifetimes (peak 53,084,160):
//   [0,10485760)          Xw (k_prep..k_qkv)  then AO (k_attn..k_out_ln)
//   [10485760,11534336)   bf16 weights (all)
//   [11534336,42991616)   Qb/Kb/VbT (k_qkv..k_attn); then Yn (k_out_ln..k_fc1) @22020096
//   [42991616,49545216)   biasPh bf16 C-frag-permuted (k_prep..k_attn)
//   [32505856,53084160)   G (k_fc1..k_fc2) — overlaps VbT/biasPh, disjoint lifetime

using f32x4 = __attribute__((ext_vector_type(4))) float;
using s16x8 = __attribute__((ext_vector_type(8))) short;

__device__ __forceinline__ ushort f2b(float f) {            // RNE (cold paths)
  union { float f; unsigned u; } v; v.f = f;
  return (ushort)((v.u + 0x7FFFu + ((v.u >> 16) & 1u)) >> 16);
}
__device__ __forceinline__ ushort f2b_fast(float f) {       // round-half-up, 1-2 VALU
  union { float f; unsigned u; } v; v.f = f;
  return (ushort)((v.u + 0x8000u) >> 16);
}
__device__ __forceinline__ float b2f(ushort u) {
  union { unsigned u; float f; } v; v.u = ((unsigned)u) << 16; return v.f;
}
__device__ __forceinline__ float lo2f(unsigned w) {
  union { unsigned u; float f; } v; v.u = w << 16; return v.f;
}
__device__ __forceinline__ float hi2f(unsigned w) {
  union { unsigned u; float f; } v; v.u = w & 0xffff0000u; return v.f;
}

__device__ __forceinline__ void gld16(const void* g, void* l) {
  __builtin_amdgcn_global_load_lds((const __attribute__((address_space(1))) void*)g,
                                   (__attribute__((address_space(3))) void*)l, 16, 0, 0);
}

// ---------------- shared 128x128 MFMA GEMM core ----------------
template<int KB>
__device__ __forceinline__ void gemm_core(const ushort* __restrict__ A, int lda,
                                          const ushort* __restrict__ B, int ldb,
                                          f32x4 acc[4][4]) {
  __shared__ ushort As[128 * 64];
  __shared__ ushort Bs[128 * 64];
  const int tid = threadIdx.x;
  const int lane = tid & 63;
  const int wv = tid >> 6;
  const int wr = (wv >> 1) * 64;
  const int wc = (wv & 1) * 64;
  const int srow = (lane >> 3);
  const int sg = ((lane & 7) ^ (srow & 7)) * 8;
  f32x4 zero = {0.f, 0.f, 0.f, 0.f};
#pragma unroll
  for (int mt = 0; mt < 4; ++mt)
#pragma unroll
    for (int nt = 0; nt < 4; ++nt) acc[mt][nt] = zero;

  for (int kb = 0; kb < KB; ++kb) {
#pragma unroll
    for (int j = 0; j < 4; ++j) {
      int r0 = wv * 32 + j * 8;
      int row = r0 + srow;
      gld16(A + row * lda + kb * 64 + sg, &As[r0 * 64]);
      gld16(B + row * ldb + kb * 64 + sg, &Bs[r0 * 64]);
    }
    __syncthreads();
#pragma unroll
    for (int ks = 0; ks < 2; ++ks) {
      s16x8 af[4], bfr[4];
      const int G = ks * 4 + (lane >> 4);
#pragma unroll
      for (int mt = 0; mt < 4; ++mt) {
        int row = wr + mt * 16 + (lane & 15);
        af[mt] = *(const s16x8*)&As[row * 64 + (G ^ (row & 7)) * 8];
      }
#pragma unroll
      for (int nt = 0; nt < 4; ++nt) {
        int row = wc + nt * 16 + (lane & 15);
        bfr[nt] = *(const s16x8*)&Bs[row * 64 + (G ^ (row & 7)) * 8];
      }
#pragma unroll
      for (int mt = 0; mt < 4; ++mt)
#pragma unroll
        for (int nt = 0; nt < 4; ++nt)
          acc[mt][nt] = __builtin_amdgcn_mfma_f32_16x16x32_bf16(af[mt], bfr[nt], acc[mt][nt], 0, 0, 0);
    }
    __syncthreads();
  }
}

// ---------------- kernel 1: gather + weight casts + permuted bias build ----------------
__global__ __launch_bounds__(256) void k_prep(const float* __restrict__ x,
                                              const float* __restrict__ wqkv,
                                              const float* __restrict__ wout,
                                              const float* __restrict__ w1,
                                              const float* __restrict__ w2,
                                              const float* __restrict__ table,
                                              ushort* __restrict__ Xw,
                                              ushort* __restrict__ wqkvb,
                                              ushort* __restrict__ woutb,
                                              ushort* __restrict__ w1b,
                                              ushort* __restrict__ w2b,
                                              ushort* __restrict__ biasPh) {
  __shared__ ushort smem[64 * 264];
  const int bid = blockIdx.x, tid = threadIdx.x;
  if (bid < 320) {
    ushort (*Ls)[264] = (ushort(*)[264])smem;
    const int t0 = bid * 64;
    const int w = t0 / 640;
    const int tokbase = t0 - w * 640;
    const int b = w >> 4, wh = (w >> 2) & 3, ww = w & 3;
    for (int i = tid; i < 64 * 256; i += 256) {
      int c = i >> 6, tl = i & 63;
      int tok = tokbase + tl;
      ushort val = 0;
      if (tok < 625) {
        int ii = tok / 25, jj = tok - ii * 25;
        val = f2b(x[((b * 256 + c) * 100 + wh * 25 + ii) * 100 + ww * 25 + jj]);
      }
      Ls[tl][c] = val;
    }
    __syncthreads();
    for (int i = tid; i < 64 * 32; i += 256) {
      int tl = i >> 5, g = (i & 31) * 8;
      *(uint4*)(Xw + (t0 + tl) * 256 + g) = *(const uint4*)&Ls[tl][g];
    }
  } else if (bid < 832) {
    int v = (bid - 320) * 1024 + tid * 4;
    const float* src; ushort* dst; int off;
    if (v < 196608)      { src = wqkv; dst = wqkvb; off = v; }
    else if (v < 262144) { src = wout; dst = woutb; off = v - 196608; }
    else if (v < 393216) { src = w1;   dst = w1b;   off = v - 262144; }
    else                 { src = w2;   dst = w2b;   off = v - 393216; }
    float4 f = *(const float4*)(src + off);
    ushort4 u; u.x = f2b(f.x); u.y = f2b(f.y); u.z = f2b(f.z); u.w = f2b(f.w);
    *(ushort4*)(dst + off) = u;
  } else {
    // bias permuted to attn C-frag order, *log2e, col-mask folded in.
    float* tl = (float*)smem;
    const int q = bid - 832;
    const int h = q / 40, t = q - (q / 40) * 40;
    for (int i = tid; i < 2401; i += 256) tl[i] = table[i * 8 + h] * 1.4426950408889634f;
    __syncthreads();
    const int lane = tid >> 2, rr = tid & 3;
    const int quad = lane >> 4, cl = lane & 15;
    int row = t * 16 + quad * 4 + rr;
    int rowg = (row < 625) ? row : 0;
    const int ri = rowg / 25, ci = rowg - ri * 25;
    for (int cc = 0; cc < 4; ++cc)
      for (int cp = 0; cp < 5; ++cp)
#pragma unroll
        for (int codd = 0; codd < 2; ++codd) {
          int col = cc * 160 + (cp * 2 + codd) * 16 + cl;
          float v = -1e30f;
          if (col < 625) {
            int rj = col / 25, cj = col - rj * 25;
            v = tl[(ri - rj + 24) * 49 + (ci - cj + 24)];
          }
          biasPh[((((h * 40 + t) * 4 + cc) * 5 + cp) * 64 + lane) * 8 + codd * 4 + rr] = f2b(v);
        }
  }
}

// ---------------- kernel 2: QKV projection ----------------
// Q,K stored (w,h,tok,ch); V stored TRANSPOSED (w,h,ch,tok) — attn reads V^T
// B-frags straight from global. C-frag holds 4 consecutive toks per lane ->
// V store is one packed 8B store per (mt,nt).
__global__ __launch_bounds__(256) void k_qkv(const ushort* __restrict__ Xw,
                                             const ushort* __restrict__ Wb,
                                             ushort* __restrict__ Qb,
                                             ushort* __restrict__ Kb,
                                             ushort* __restrict__ VbT) {
  f32x4 acc[4][4];
  gemm_core<4>(Xw + blockIdx.x * 128 * 256, 256, Wb + blockIdx.y * 128 * 256, 256, acc);
  const int lane = threadIdx.x & 63, wv = threadIdx.x >> 6;
  const int wr = (wv >> 1) * 64, wc = (wv & 1) * 64;
  const int which = blockIdx.y >> 1;             // 0=Q 1=K 2=V (wave-uniform)
  const float QSC = 0.17677669529663687f * 1.4426950408889634f;
#pragma unroll
  for (int mt = 0; mt < 4; ++mt) {
#pragma unroll
    for (int nt = 0; nt < 4; ++nt) {
      int n = blockIdx.y * 128 + wc + nt * 16 + (lane & 15);
      int h = (n >> 5) & 7, ch = n & 31;
      int m0 = blockIdx.x * 128 + wr + mt * 16 + (lane >> 4) * 4;
      int w = m0 / 640, tok0 = m0 - w * 640;
      if (which == 2) {
        ushort4 pk;
        pk.x = f2b_fast(acc[mt][nt][0]); pk.y = f2b_fast(acc[mt][nt][1]);
        pk.z = f2b_fast(acc[mt][nt][2]); pk.w = f2b_fast(acc[mt][nt][3]);
        *(ushort4*)(VbT + (((w << 3) + h) * 32 + ch) * 640 + tok0) = pk;
      } else {
        ushort* dst = which == 0 ? Qb : Kb;
        float sc = which == 0 ? QSC : 1.f;
#pragma unroll
        for (int r = 0; r < 4; ++r)
          dst[(((w << 3) + h) * 640 + tok0 + r) * 32 + ch] = f2b_fast(acc[mt][nt][r] * sc);
      }
    }
  }
}

// ---------------- kernel 3: fused windowed attention — barrier-free, XCD-pinned ----------------
// 2560 blocks; h = bid&7 -> with round-robin dispatch each XCD owns one head:
// per-XCD working set K+V^T+bias = 3.4 MB < 4 MB L2 -> L2-resident.
// No LDS V stage (global V^T), no __syncthreads anywhere; LDS = Pw only (21 KB).
__global__ __launch_bounds__(256, 4) void k_attn(const ushort* __restrict__ Qb,
                                                 const ushort* __restrict__ Kb,
                                                 const ushort* __restrict__ VbT,
                                                 const ushort* __restrict__ biasPh,
                                                 ushort* __restrict__ AO) {
  __shared__ ushort Pw[4][16][164];     // 20992 B, wave-private P chunks
  const int tid = threadIdx.x;
  const int lane = tid & 63;
  const int wv = tid >> 6;
  const int quad = lane >> 4;
  const int cl = lane & 15;
  const int bid = blockIdx.x;
  const int h = bid & 7;                // XCD pin
  const int rem = bid >> 3;             // 0..319
  const int win = rem / 10;
  const int tg = rem - win * 10;
  const ushort* Qg = Qb + (win * 8 + h) * 20480;
  const ushort* Kg = Kb + (win * 8 + h) * 20480;
  const ushort* Vt = VbT + (win * 8 + h) * 20480;   // [ch][640]

  const int t = tg * 4 + wv;            // this wave's q-tile (0..39)
  const s16x8 qf = *(const s16x8*)(Qg + (t * 16 + cl) * 32 + quad * 8);
  const f32x4 zero = {0.f, 0.f, 0.f, 0.f};
  f32x4 o0 = zero, o1 = zero;
  float osum[4] = {0.f, 0.f, 0.f, 0.f};

  for (int cc = 0; cc < 4; ++cc) {
    // --- S = Q K^T for key cols [cc*160, cc*160+160) ---
    f32x4 s[10];
#pragma unroll
    for (int c = 0; c < 10; ++c) {
      s16x8 kf = *(const s16x8*)(Kg + (cc * 160 + c * 16 + cl) * 32 + quad * 8);
      s[c] = __builtin_amdgcn_mfma_f32_16x16x32_bf16(qf, kf, zero, 0, 0, 0);
    }
    // --- bias in C-frag order: 5 coalesced 16B loads ---
    const ushort* bp = biasPh + (((h * 40 + t) * 4 + cc) * 5) * 512 + lane * 8;
#pragma unroll
    for (int cp = 0; cp < 5; ++cp) {
      s16x8 bb = *(const s16x8*)(bp + cp * 512);
      const unsigned* bw = (const unsigned*)&bb;
#pragma unroll
      for (int codd = 0; codd < 2; ++codd) {
        int c = cp * 2 + codd;
        unsigned w0 = bw[codd * 2], w1 = bw[codd * 2 + 1];
        s[c][0] += lo2f(w0); s[c][1] += hi2f(w0);
        s[c][2] += lo2f(w1); s[c][3] += hi2f(w1);
      }
    }
    // --- exp2 (no max; scores tiny, mask via -1e30 bias), P -> wave-private LDS ---
#pragma unroll
    for (int c = 0; c < 10; ++c)
#pragma unroll
      for (int r = 0; r < 4; ++r) {
        float p = exp2f(s[c][r]);
        osum[r] += p;
        Pw[wv][quad * 4 + r][c * 16 + cl] = f2b_fast(p);
      }
    // --- O += P V (P read by same wave -> lgkmcnt orders it; V^T from global/L2) ---
#pragma unroll
    for (int kc = 0; kc < 5; ++kc) {
      s16x8 pf = *(const s16x8*)&Pw[wv][cl][kc * 32 + quad * 8];
      s16x8 vf0 = *(const s16x8*)(Vt + cl * 640 + cc * 160 + kc * 32 + quad * 8);
      s16x8 vf1 = *(const s16x8*)(Vt + (16 + cl) * 640 + cc * 160 + kc * 32 + quad * 8);
      o0 = __builtin_amdgcn_mfma_f32_16x16x32_bf16(pf, vf0, o0, 0, 0, 0);
      o1 = __builtin_amdgcn_mfma_f32_16x16x32_bf16(pf, vf1, o1, 0, 0, 0);
    }
  }
  // --- normalize + store (head-major concat) ---
#pragma unroll
  for (int r = 0; r < 4; ++r) {
    float ss = osum[r];
    ss += __shfl_xor(ss, 1, 64); ss += __shfl_xor(ss, 2, 64);
    ss += __shfl_xor(ss, 4, 64); ss += __shfl_xor(ss, 8, 64);
    float inv = 1.f / ss;
    int tok = t * 16 + quad * 4 + r;
    if (tok < 625) {
      int base = (win * 640 + tok) * 256 + h * 32;
      AO[base + cl] = f2b_fast(o0[r] * inv);
      AO[base + 16 + cl] = f2b_fast(o1[r] * inv);
    }
  }
}

// ---------------- kernel 4: out-projection + un-partition + LayerNorm ----------------
// 64 tokens x 256 ch per block -> grid 320 (was 160: under-dispatched).
__global__ __launch_bounds__(256, 2) void k_out_ln(const ushort* __restrict__ AO,
                                                   const ushort* __restrict__ Wb,
                                                   const float* __restrict__ gamma,
                                                   const float* __restrict__ beta,
                                                   ushort* __restrict__ Yn) {
  __shared__ ushort As[64 * 64];
  __shared__ ushort Bs[256 * 64];
  __shared__ float red[2][64][2];
  const int tid = threadIdx.x;
  const int lane = tid & 63;
  const int wv = tid >> 6;
  const int wr = (wv >> 1) * 32, wc = (wv & 1) * 128;
  const int quad = lane >> 4, cl = lane & 15;
  const int srow = lane >> 3;
  const int sg = ((lane & 7) ^ (srow & 7)) * 8;
  f32x4 zero = {0.f, 0.f, 0.f, 0.f};
  f32x4 acc[2][8];
#pragma unroll
  for (int mt = 0; mt < 2; ++mt)
#pragma unroll
    for (int nt = 0; nt < 8; ++nt) acc[mt][nt] = zero;

  const ushort* A = AO + blockIdx.x * 64 * 256;
  for (int kb = 0; kb < 4; ++kb) {
#pragma unroll
    for (int i = 0; i < 10; ++i) {
      int r0 = (wv + i * 4) * 8;           // 0..312 step 8, wave-uniform
      int row = r0 + srow;
      if (r0 < 64) gld16(A + row * 256 + kb * 64 + sg, &As[r0 * 64]);
      else         gld16(Wb + (row - 64) * 256 + kb * 64 + sg, &Bs[(r0 - 64) * 64]);
    }
    __syncthreads();
#pragma unroll
    for (int ks = 0; ks < 2; ++ks) {
      s16x8 af[2], bfr[8];
      const int G = ks * 4 + quad;
#pragma unroll
      for (int mt = 0; mt < 2; ++mt) {
        int row = wr + mt * 16 + cl;
        af[mt] = *(const s16x8*)&As[row * 64 + (G ^ (row & 7)) * 8];
      }
#pragma unroll
      for (int nt = 0; nt < 8; ++nt) {
        int row = wc + nt * 16 + cl;
        bfr[nt] = *(const s16x8*)&Bs[row * 64 + (G ^ (row & 7)) * 8];
      }
#pragma unroll
      for (int mt = 0; mt < 2; ++mt)
#pragma unroll
        for (int nt = 0; nt < 8; ++nt)
          acc[mt][nt] = __builtin_amdgcn_mfma_f32_16x16x32_bf16(af[mt], bfr[nt], acc[mt][nt], 0, 0, 0);
    }
    __syncthreads();
  }
#pragma unroll
  for (int mt = 0; mt < 2; ++mt)
#pragma unroll
    for (int r = 0; r < 4; ++r) {
      float s = 0.f, ss = 0.f;
#pragma unroll
      for (int nt = 0; nt < 8; ++nt) { float v = acc[mt][nt][r]; s += v; ss += v * v; }
      s += __shfl_xor(s, 1, 64); ss += __shfl_xor(ss, 1, 64);
      s += __shfl_xor(s, 2, 64); ss += __shfl_xor(ss, 2, 64);
      s += __shfl_xor(s, 4, 64); ss += __shfl_xor(ss, 4, 64);
      s += __shfl_xor(s, 8, 64); ss += __shfl_xor(ss, 8, 64);
      if (cl == 0) {
        int row = wr + mt * 16 + quad * 4 + r;
        red[wc >> 7][row][0] = s;
        red[wc >> 7][row][1] = ss;
      }
    }
  __syncthreads();
  float g[8], bt[8];
#pragma unroll
  for (int nt = 0; nt < 8; ++nt) { int n = wc + nt * 16 + cl; g[nt] = gamma[n]; bt[nt] = beta[n]; }
  const int m0 = blockIdx.x * 64;
#pragma unroll
  for (int mt = 0; mt < 2; ++mt)
#pragma unroll
    for (int r = 0; r < 4; ++r) {
      int row = wr + mt * 16 + quad * 4 + r;
      int m = m0 + row;
      int w = m / 640, tok = m - w * 640;
      if (tok < 625) {
        float sum = red[0][row][0] + red[1][row][0];
        float ssum = red[0][row][1] + red[1][row][1];
        float mean = sum * 0.00390625f;
        float var = ssum * 0.00390625f - mean * mean;
        float rstd = rsqrtf(var + 1e-5f);
        int b = w >> 4, whh = (w >> 2) & 3, www = w & 3;
        int ii = tok / 25, jj = tok - ii * 25;
        int p = (whh * 25 + ii) * 100 + www * 25 + jj;
        ushort* dst = Yn + (b * 10000 + p) * 256;
#pragma unroll
        for (int nt = 0; nt < 8; ++nt) {
          float v = (acc[mt][nt][r] - mean) * rstd * g[nt] + bt[nt];
          dst[wc + nt * 16 + cl] = f2b_fast(v);
        }
      }
    }
}

// ---------------- kernel 5: fc1 + exact GELU ----------------
__global__ __launch_bounds__(256) void k_fc1(const ushort* __restrict__ Yn,
                                             const ushort* __restrict__ W1b,
                                             const float* __restrict__ b1,
                                             ushort* __restrict__ G) {
  f32x4 acc[4][4];
  gemm_core<4>(Yn + blockIdx.x * 128 * 256, 256, W1b + blockIdx.y * 128 * 256, 256, acc);
  const int lane = threadIdx.x & 63, wv = threadIdx.x >> 6;
  const int wr = (wv >> 1) * 64, wc = (wv & 1) * 64;
#pragma unroll
  for (int mt = 0; mt < 4; ++mt)
#pragma unroll
    for (int nt = 0; nt < 4; ++nt) {
      int n = blockIdx.y * 128 + wc + nt * 16 + (lane & 15);
      float bias = b1[n];
#pragma unroll
      for (int r = 0; r < 4; ++r) {
        int m = blockIdx.x * 128 + wr + mt * 16 + (lane >> 4) * 4 + r;
        float v = acc[mt][nt][r] + bias;
        v = 0.5f * v * (1.f + erff(v * 0.70710678118f));
        G[m * 512 + n] = f2b_fast(v);
      }
    }
}

// ---------------- kernel 6: fc2 + residual, swapped roles (M=ch, N=tok) ----------------
__global__ __launch_bounds__(256) void k_fc2(const ushort* __restrict__ W2b,
                                             const ushort* __restrict__ G,
                                             const float* __restrict__ b2,
                                             const float* __restrict__ x,
                                             float* __restrict__ out) {
  f32x4 acc[4][4];
  gemm_core<8>(W2b + blockIdx.x * 128 * 512, 512, G + blockIdx.y * 128 * 512, 512, acc);
  const int lane = threadIdx.x & 63, wv = threadIdx.x >> 6;
  const int wr = (wv >> 1) * 64, wc = (wv & 1) * 64;
#pragma unroll
  for (int mt = 0; mt < 4; ++mt)
#pragma unroll
    for (int nt = 0; nt < 4; ++nt) {
      int t = blockIdx.y * 128 + wc + nt * 16 + (lane & 15);
      if (t < 20000) {
        int b = t / 10000, p = t - b * 10000;
#pragma unroll
        for (int r = 0; r < 4; ++r) {
          int c = blockIdx.x * 128 + wr + mt * 16 + (lane >> 4) * 4 + r;
          int idx = (b * 256 + c) * 10000 + p;
          out[idx] = x[idx] + acc[mt][nt][r] + b2[c];
        }
      }
    }
}

extern "C" void kernel_launch(void* const* d_in, const int* in_sizes, int n_in,
                              void* d_out, int out_size, void* d_ws, size_t ws_size,
                              hipStream_t stream) {
  const float* x     = (const float*)d_in[0];
  const float* wqkv  = (const float*)d_in[1];
  const float* wout  = (const float*)d_in[2];
  const float* bias  = (const float*)d_in[3];
  const float* gamma = (const float*)d_in[4];
  const float* beta  = (const float*)d_in[5];
  const float* w1    = (const float*)d_in[6];
  const float* b1    = (const float*)d_in[7];
  const float* w2    = (const float*)d_in[8];
  const float* b2    = (const float*)d_in[9];
  float* out = (float*)d_out;
  char* ws = (char*)d_ws;

  ushort* Xw    = (ushort*)(ws + 0);
  ushort* AO    = Xw;
  ushort* wqkvb = (ushort*)(ws + 10485760);
  ushort* woutb = (ushort*)(ws + 10878976);
  ushort* w1b   = (ushort*)(ws + 11010048);
  ushort* w2b   = (ushort*)(ws + 11272192);
  ushort* Qb    = (ushort*)(ws + 11534336);
  ushort* Kb    = (ushort*)(ws + 22020096);
  ushort* VbT   = (ushort*)(ws + 32505856);
  ushort* biasPh= (ushort*)(ws + 42991616);
  ushort* Yn    = (ushort*)(ws + 22020096);     // alias Kb (dead after attn)
  ushort* G     = (ushort*)(ws + 32505856);     // alias VbT+biasPh (post-attn)

  k_prep  <<<1152, 256, 0, stream>>>(x, wqkv, wout, w1, w2, bias,
                                     Xw, wqkvb, woutb, w1b, w2b, biasPh);
  k_qkv   <<<dim3(160, 6), 256, 0, stream>>>(Xw, wqkvb, Qb, Kb, VbT);
  k_attn  <<<2560, 256, 0, stream>>>(Qb, Kb, VbT, biasPh, AO);
  k_out_ln<<<320, 256, 0, stream>>>(AO, woutb, gamma, beta, Yn);
  k_fc1   <<<dim3(157, 4), 256, 0, stream>>>(Yn, w1b, b1, G);
  k_fc2   <<<dim3(2, 157), 256, 0, stream>>>(w2b, G, b2, x, out);
}

// Round 5
// 223.487 us; speedup vs baseline: 1.1254x; 1.1254x over previous
//
#include <hip/hip_runtime.h>

// BEV transformer block, MI355X/gfx950.  Round 5.
// ws layout (bytes) — regions aliased across kernel lifetimes (peak 53,084,160):
//   [0,10485760)          Xw (k_prep..k_qkv)  then AO (k_attn..k_out_ln)
//   [10485760,11534336)   bf16 weights (all)
//   [11534336,42991616)   Qb/Kb/VbT (k_qkv..k_attn); then Yn (k_out_ln..k_fc1) @22020096
//   [42991616,49545216)   biasPh bf16 C-frag-permuted (k_prep..k_attn)
//   [32505856,53084160)   G (k_fc1..k_fc2) — overlaps VbT/biasPh, disjoint lifetime

using f32x4 = __attribute__((ext_vector_type(4))) float;
using s16x8 = __attribute__((ext_vector_type(8))) short;

__device__ __forceinline__ ushort f2b(float f) {            // RNE (cold paths)
  union { float f; unsigned u; } v; v.f = f;
  return (ushort)((v.u + 0x7FFFu + ((v.u >> 16) & 1u)) >> 16);
}
__device__ __forceinline__ ushort f2b_fast(float f) {       // round-half-up
  union { float f; unsigned u; } v; v.f = f;
  return (ushort)((v.u + 0x8000u) >> 16);
}
__device__ __forceinline__ float b2f(ushort u) {
  union { unsigned u; float f; } v; v.u = ((unsigned)u) << 16; return v.f;
}
__device__ __forceinline__ float lo2f(unsigned w) {
  union { unsigned u; float f; } v; v.u = w << 16; return v.f;
}
__device__ __forceinline__ float hi2f(unsigned w) {
  union { unsigned u; float f; } v; v.u = w & 0xffff0000u; return v.f;
}

__device__ __forceinline__ void gld16(const void* g, void* l) {
  __builtin_amdgcn_global_load_lds((const __attribute__((address_space(1))) void*)g,
                                   (__attribute__((address_space(3))) void*)l, 16, 0, 0);
}

// ---------------- shared 128x128 MFMA GEMM core ----------------
template<int KB>
__device__ __forceinline__ void gemm_core(const ushort* __restrict__ A, int lda,
                                          const ushort* __restrict__ B, int ldb,
                                          f32x4 acc[4][4]) {
  __shared__ ushort As[128 * 64];
  __shared__ ushort Bs[128 * 64];
  const int tid = threadIdx.x;
  const int lane = tid & 63;
  const int wv = tid >> 6;
  const int wr = (wv >> 1) * 64;
  const int wc = (wv & 1) * 64;
  const int srow = (lane >> 3);
  const int sg = ((lane & 7) ^ (srow & 7)) * 8;
  f32x4 zero = {0.f, 0.f, 0.f, 0.f};
#pragma unroll
  for (int mt = 0; mt < 4; ++mt)
#pragma unroll
    for (int nt = 0; nt < 4; ++nt) acc[mt][nt] = zero;

  for (int kb = 0; kb < KB; ++kb) {
#pragma unroll
    for (int j = 0; j < 4; ++j) {
      int r0 = wv * 32 + j * 8;
      int row = r0 + srow;
      gld16(A + row * lda + kb * 64 + sg, &As[r0 * 64]);
      gld16(B + row * ldb + kb * 64 + sg, &Bs[r0 * 64]);
    }
    __syncthreads();
#pragma unroll
    for (int ks = 0; ks < 2; ++ks) {
      s16x8 af[4], bfr[4];
      const int G = ks * 4 + (lane >> 4);
#pragma unroll
      for (int mt = 0; mt < 4; ++mt) {
        int row = wr + mt * 16 + (lane & 15);
        af[mt] = *(const s16x8*)&As[row * 64 + (G ^ (row & 7)) * 8];
      }
#pragma unroll
      for (int nt = 0; nt < 4; ++nt) {
        int row = wc + nt * 16 + (lane & 15);
        bfr[nt] = *(const s16x8*)&Bs[row * 64 + (G ^ (row & 7)) * 8];
      }
#pragma unroll
      for (int mt = 0; mt < 4; ++mt)
#pragma unroll
        for (int nt = 0; nt < 4; ++nt)
          acc[mt][nt] = __builtin_amdgcn_mfma_f32_16x16x32_bf16(af[mt], bfr[nt], acc[mt][nt], 0, 0, 0);
    }
    __syncthreads();
  }
}

// ---------------- kernel 1: gather + weight casts + permuted bias build ----------------
__global__ __launch_bounds__(256) void k_prep(const float* __restrict__ x,
                                              const float* __restrict__ wqkv,
                                              const float* __restrict__ wout,
                                              const float* __restrict__ w1,
                                              const float* __restrict__ w2,
                                              const float* __restrict__ table,
                                              ushort* __restrict__ Xw,
                                              ushort* __restrict__ wqkvb,
                                              ushort* __restrict__ woutb,
                                              ushort* __restrict__ w1b,
                                              ushort* __restrict__ w2b,
                                              ushort* __restrict__ biasPh) {
  __shared__ ushort smem[64 * 264];
  const int bid = blockIdx.x, tid = threadIdx.x;
  if (bid < 320) {
    ushort (*Ls)[264] = (ushort(*)[264])smem;
    const int t0 = bid * 64;
    const int w = t0 / 640;
    const int tokbase = t0 - w * 640;
    const int b = w >> 4, wh = (w >> 2) & 3, ww = w & 3;
    for (int i = tid; i < 64 * 256; i += 256) {
      int c = i >> 6, tl = i & 63;
      int tok = tokbase + tl;
      ushort val = 0;
      if (tok < 625) {
        int ii = tok / 25, jj = tok - ii * 25;
        val = f2b(x[((b * 256 + c) * 100 + wh * 25 + ii) * 100 + ww * 25 + jj]);
      }
      Ls[tl][c] = val;
    }
    __syncthreads();
    for (int i = tid; i < 64 * 32; i += 256) {
      int tl = i >> 5, g = (i & 31) * 8;
      *(uint4*)(Xw + (t0 + tl) * 256 + g) = *(const uint4*)&Ls[tl][g];
    }
  } else if (bid < 832) {
    int v = (bid - 320) * 1024 + tid * 4;
    const float* src; ushort* dst; int off;
    if (v < 196608)      { src = wqkv; dst = wqkvb; off = v; }
    else if (v < 262144) { src = wout; dst = woutb; off = v - 196608; }
    else if (v < 393216) { src = w1;   dst = w1b;   off = v - 262144; }
    else                 { src = w2;   dst = w2b;   off = v - 393216; }
    float4 f = *(const float4*)(src + off);
    ushort4 u; u.x = f2b(f.x); u.y = f2b(f.y); u.z = f2b(f.z); u.w = f2b(f.w);
    *(ushort4*)(dst + off) = u;
  } else {
    // bias permuted to attn C-frag order, *log2e, col-mask folded in.
    float* tl = (float*)smem;
    const int q = bid - 832;
    const int h = q / 40, t = q - (q / 40) * 40;
    for (int i = tid; i < 2401; i += 256) tl[i] = table[i * 8 + h] * 1.4426950408889634f;
    __syncthreads();
    const int lane = tid >> 2, rr = tid & 3;
    const int quad = lane >> 4, cl = lane & 15;
    int row = t * 16 + quad * 4 + rr;
    int rowg = (row < 625) ? row : 0;
    const int ri = rowg / 25, ci = rowg - ri * 25;
    for (int cc = 0; cc < 4; ++cc)
      for (int cp = 0; cp < 5; ++cp)
#pragma unroll
        for (int codd = 0; codd < 2; ++codd) {
          int col = cc * 160 + (cp * 2 + codd) * 16 + cl;
          float v = -1e30f;
          if (col < 625) {
            int rj = col / 25, cj = col - rj * 25;
            v = tl[(ri - rj + 24) * 49 + (ci - cj + 24)];
          }
          biasPh[((((h * 40 + t) * 4 + cc) * 5 + cp) * 64 + lane) * 8 + codd * 4 + rr] = f2b(v);
        }
  }
}

// ---------------- kernel 2: QKV projection ----------------
__global__ __launch_bounds__(256) void k_qkv(const ushort* __restrict__ Xw,
                                             const ushort* __restrict__ Wb,
                                             ushort* __restrict__ Qb,
                                             ushort* __restrict__ Kb,
                                             ushort* __restrict__ VbT) {
  f32x4 acc[4][4];
  gemm_core<4>(Xw + blockIdx.x * 128 * 256, 256, Wb + blockIdx.y * 128 * 256, 256, acc);
  const int lane = threadIdx.x & 63, wv = threadIdx.x >> 6;
  const int wr = (wv >> 1) * 64, wc = (wv & 1) * 64;
  const int which = blockIdx.y >> 1;
  const float QSC = 0.17677669529663687f * 1.4426950408889634f;
#pragma unroll
  for (int mt = 0; mt < 4; ++mt) {
#pragma unroll
    for (int nt = 0; nt < 4; ++nt) {
      int n = blockIdx.y * 128 + wc + nt * 16 + (lane & 15);
      int h = (n >> 5) & 7, ch = n & 31;
      int m0 = blockIdx.x * 128 + wr + mt * 16 + (lane >> 4) * 4;
      int w = m0 / 640, tok0 = m0 - w * 640;
      if (which == 2) {
        ushort4 pk;
        pk.x = f2b_fast(acc[mt][nt][0]); pk.y = f2b_fast(acc[mt][nt][1]);
        pk.z = f2b_fast(acc[mt][nt][2]); pk.w = f2b_fast(acc[mt][nt][3]);
        *(ushort4*)(VbT + (((w << 3) + h) * 32 + ch) * 640 + tok0) = pk;
      } else {
        ushort* dst = which == 0 ? Qb : Kb;
        float sc = which == 0 ? QSC : 1.f;
#pragma unroll
        for (int r = 0; r < 4; ++r)
          dst[(((w << 3) + h) * 640 + tok0 + r) * 32 + ch] = f2b_fast(acc[mt][nt][r] * sc);
      }
    }
  }
}

// ---------------- kernel 3: fused windowed attention — 2 q-tiles/wave, prefetched ----------------
// 1280 blocks = 32win x 5tg x 8h (h=bid&7 XCD pin). Each wave owns q-tiles
// t0=tg*8+wv*2 and t0+1, sharing K and V fragments (halves L2 traffic, 2x ILP).
// All K/V/bias loads hoisted to top of each cc chunk (registers, (256,2) budget).
// Row-sums via ones-MFMA (C-layout matches o rows -> no shuffles).
// Bias enters as the MFMA C-operand. No __syncthreads in the loop.
__global__ __launch_bounds__(256, 2) void k_attn(const ushort* __restrict__ Qb,
                                                 const ushort* __restrict__ Kb,
                                                 const ushort* __restrict__ VbT,
                                                 const ushort* __restrict__ biasPh,
                                                 ushort* __restrict__ AO) {
  __shared__ ushort Pw[8][16][164];     // 41984 B, wave-private P chunks (2 per wave)
  const int tid = threadIdx.x;
  const int lane = tid & 63;
  const int wv = tid >> 6;
  const int quad = lane >> 4;
  const int cl = lane & 15;
  const int bid = blockIdx.x;
  const int h = bid & 7;                // XCD pin
  const int rem = bid >> 3;             // 0..159
  const int win = rem / 5;
  const int tg = rem - win * 5;
  const ushort* Qg = Qb + (win * 8 + h) * 20480;
  const ushort* Kg = Kb + (win * 8 + h) * 20480;
  const ushort* Vt = VbT + (win * 8 + h) * 20480;   // [ch][640]

  const int t0 = tg * 8 + wv * 2;
  const s16x8 qf0 = *(const s16x8*)(Qg + (t0 * 16 + cl) * 32 + quad * 8);
  const s16x8 qf1 = *(const s16x8*)(Qg + ((t0 + 1) * 16 + cl) * 32 + quad * 8);
  s16x8 ones;
#pragma unroll
  for (int j = 0; j < 8; ++j) ones[j] = (short)0x3F80;    // bf16 1.0

  const f32x4 zero = {0.f, 0.f, 0.f, 0.f};
  f32x4 o00 = zero, o01 = zero, o10 = zero, o11 = zero;
  f32x4 sum0 = zero, sum1 = zero;

#pragma unroll
  for (int cc = 0; cc < 4; ++cc) {
    // --- prefetch: K frags (shared), V frags (shared), independent of P ---
    s16x8 kf[10];
#pragma unroll
    for (int c = 0; c < 10; ++c)
      kf[c] = *(const s16x8*)(Kg + (cc * 160 + c * 16 + cl) * 32 + quad * 8);
    s16x8 vf0[5], vf1[5];
#pragma unroll
    for (int kc = 0; kc < 5; ++kc) {
      vf0[kc] = *(const s16x8*)(Vt + cl * 640 + cc * 160 + kc * 32 + quad * 8);
      vf1[kc] = *(const s16x8*)(Vt + (16 + cl) * 640 + cc * 160 + kc * 32 + quad * 8);
    }
#pragma unroll
    for (int tl = 0; tl < 2; ++tl) {
      const int t = t0 + tl;
      const s16x8 qf = tl ? qf1 : qf0;
      // --- bias as MFMA C-operand (log2-domain, mask folded) ---
      const ushort* bp = biasPh + (((h * 40 + t) * 4 + cc) * 5) * 512 + lane * 8;
      f32x4 s[10];
#pragma unroll
      for (int cp = 0; cp < 5; ++cp) {
        s16x8 bb = *(const s16x8*)(bp + cp * 512);
        const unsigned* bw = (const unsigned*)&bb;
        f32x4 c0, c1;
        c0[0] = lo2f(bw[0]); c0[1] = hi2f(bw[0]); c0[2] = lo2f(bw[1]); c0[3] = hi2f(bw[1]);
        c1[0] = lo2f(bw[2]); c1[1] = hi2f(bw[2]); c1[2] = lo2f(bw[3]); c1[3] = hi2f(bw[3]);
        s[cp * 2] = c0; s[cp * 2 + 1] = c1;
      }
#pragma unroll
      for (int c = 0; c < 10; ++c)
        s[c] = __builtin_amdgcn_mfma_f32_16x16x32_bf16(qf, kf[c], s[c], 0, 0, 0);
      // --- exp2, P -> wave-private LDS (no max: scores small, mask via -1e30) ---
#pragma unroll
      for (int c = 0; c < 10; ++c)
#pragma unroll
        for (int r = 0; r < 4; ++r)
          Pw[wv * 2 + tl][quad * 4 + r][c * 16 + cl] = f2b_fast(exp2f(s[c][r]));
      // --- PV + ones-sum (same wave wrote Pw -> lgkmcnt orders it) ---
      f32x4& o0 = tl ? o10 : o00;
      f32x4& o1 = tl ? o11 : o01;
      f32x4& sm = tl ? sum1 : sum0;
#pragma unroll
      for (int kc = 0; kc < 5; ++kc) {
        s16x8 pf = *(const s16x8*)&Pw[wv * 2 + tl][cl][kc * 32 + quad * 8];
        o0 = __builtin_amdgcn_mfma_f32_16x16x32_bf16(pf, vf0[kc], o0, 0, 0, 0);
        o1 = __builtin_amdgcn_mfma_f32_16x16x32_bf16(pf, vf1[kc], o1, 0, 0, 0);
        sm = __builtin_amdgcn_mfma_f32_16x16x32_bf16(pf, ones, sm, 0, 0, 0);
      }
    }
  }
  // --- normalize + store; sum already per-lane in matching C-layout rows ---
#pragma unroll
  for (int tl = 0; tl < 2; ++tl) {
    const f32x4& o0 = tl ? o10 : o00;
    const f32x4& o1 = tl ? o11 : o01;
    const f32x4& sm = tl ? sum1 : sum0;
#pragma unroll
    for (int r = 0; r < 4; ++r) {
      float inv = 1.f / sm[r];
      int tok = (t0 + tl) * 16 + quad * 4 + r;
      if (tok < 625) {
        int base = (win * 640 + tok) * 256 + h * 32;
        AO[base + cl] = f2b_fast(o0[r] * inv);
        AO[base + 16 + cl] = f2b_fast(o1[r] * inv);
      }
    }
  }
}

// ---------------- kernel 4: out-projection + un-partition + LayerNorm ----------------
__global__ __launch_bounds__(256, 2) void k_out_ln(const ushort* __restrict__ AO,
                                                   const ushort* __restrict__ Wb,
                                                   const float* __restrict__ gamma,
                                                   const float* __restrict__ beta,
                                                   ushort* __restrict__ Yn) {
  __shared__ ushort As[64 * 64];
  __shared__ ushort Bs[256 * 64];
  __shared__ float red[2][64][2];
  const int tid = threadIdx.x;
  const int lane = tid & 63;
  const int wv = tid >> 6;
  const int wr = (wv >> 1) * 32, wc = (wv & 1) * 128;
  const int quad = lane >> 4, cl = lane & 15;
  const int srow = lane >> 3;
  const int sg = ((lane & 7) ^ (srow & 7)) * 8;
  f32x4 zero = {0.f, 0.f, 0.f, 0.f};
  f32x4 acc[2][8];
#pragma unroll
  for (int mt = 0; mt < 2; ++mt)
#pragma unroll
    for (int nt = 0; nt < 8; ++nt) acc[mt][nt] = zero;

  const ushort* A = AO + blockIdx.x * 64 * 256;
  for (int kb = 0; kb < 4; ++kb) {
#pragma unroll
    for (int i = 0; i < 10; ++i) {
      int r0 = (wv + i * 4) * 8;
      int row = r0 + srow;
      if (r0 < 64) gld16(A + row * 256 + kb * 64 + sg, &As[r0 * 64]);
      else         gld16(Wb + (row - 64) * 256 + kb * 64 + sg, &Bs[(r0 - 64) * 64]);
    }
    __syncthreads();
#pragma unroll
    for (int ks = 0; ks < 2; ++ks) {
      s16x8 af[2], bfr[8];
      const int G = ks * 4 + quad;
#pragma unroll
      for (int mt = 0; mt < 2; ++mt) {
        int row = wr + mt * 16 + cl;
        af[mt] = *(const s16x8*)&As[row * 64 + (G ^ (row & 7)) * 8];
      }
#pragma unroll
      for (int nt = 0; nt < 8; ++nt) {
        int row = wc + nt * 16 + cl;
        bfr[nt] = *(const s16x8*)&Bs[row * 64 + (G ^ (row & 7)) * 8];
      }
#pragma unroll
      for (int mt = 0; mt < 2; ++mt)
#pragma unroll
        for (int nt = 0; nt < 8; ++nt)
          acc[mt][nt] = __builtin_amdgcn_mfma_f32_16x16x32_bf16(af[mt], bfr[nt], acc[mt][nt], 0, 0, 0);
    }
    __syncthreads();
  }
#pragma unroll
  for (int mt = 0; mt < 2; ++mt)
#pragma unroll
    for (int r = 0; r < 4; ++r) {
      float s = 0.f, ss = 0.f;
#pragma unroll
      for (int nt = 0; nt < 8; ++nt) { float v = acc[mt][nt][r]; s += v; ss += v * v; }
      s += __shfl_xor(s, 1, 64); ss += __shfl_xor(ss, 1, 64);
      s += __shfl_xor(s, 2, 64); ss += __shfl_xor(ss, 2, 64);
      s += __shfl_xor(s, 4, 64); ss += __shfl_xor(ss, 4, 64);
      s += __shfl_xor(s, 8, 64); ss += __shfl_xor(ss, 8, 64);
      if (cl == 0) {
        int row = wr + mt * 16 + quad * 4 + r;
        red[wc >> 7][row][0] = s;
        red[wc >> 7][row][1] = ss;
      }
    }
  __syncthreads();
  float g[8], bt[8];
#pragma unroll
  for (int nt = 0; nt < 8; ++nt) { int n = wc + nt * 16 + cl; g[nt] = gamma[n]; bt[nt] = beta[n]; }
  const int m0 = blockIdx.x * 64;
#pragma unroll
  for (int mt = 0; mt < 2; ++mt)
#pragma unroll
    for (int r = 0; r < 4; ++r) {
      int row = wr + mt * 16 + quad * 4 + r;
      int m = m0 + row;
      int w = m / 640, tok = m - w * 640;
      if (tok < 625) {
        float sum = red[0][row][0] + red[1][row][0];
        float ssum = red[0][row][1] + red[1][row][1];
        float mean = sum * 0.00390625f;
        float var = ssum * 0.00390625f - mean * mean;
        float rstd = rsqrtf(var + 1e-5f);
        int b = w >> 4, whh = (w >> 2) & 3, www = w & 3;
        int ii = tok / 25, jj = tok - ii * 25;
        int p = (whh * 25 + ii) * 100 + www * 25 + jj;
        ushort* dst = Yn + (b * 10000 + p) * 256;
#pragma unroll
        for (int nt = 0; nt < 8; ++nt) {
          float v = (acc[mt][nt][r] - mean) * rstd * g[nt] + bt[nt];
          dst[wc + nt * 16 + cl] = f2b_fast(v);
        }
      }
    }
}

// ---------------- kernel 5: fc1 + exact GELU ----------------
__global__ __launch_bounds__(256) void k_fc1(const ushort* __restrict__ Yn,
                                             const ushort* __restrict__ W1b,
                                             const float* __restrict__ b1,
                                             ushort* __restrict__ G) {
  f32x4 acc[4][4];
  gemm_core<4>(Yn + blockIdx.x * 128 * 256, 256, W1b + blockIdx.y * 128 * 256, 256, acc);
  const int lane = threadIdx.x & 63, wv = threadIdx.x >> 6;
  const int wr = (wv >> 1) * 64, wc = (wv & 1) * 64;
#pragma unroll
  for (int mt = 0; mt < 4; ++mt)
#pragma unroll
    for (int nt = 0; nt < 4; ++nt) {
      int n = blockIdx.y * 128 + wc + nt * 16 + (lane & 15);
      float bias = b1[n];
#pragma unroll
      for (int r = 0; r < 4; ++r) {
        int m = blockIdx.x * 128 + wr + mt * 16 + (lane >> 4) * 4 + r;
        float v = acc[mt][nt][r] + bias;
        v = 0.5f * v * (1.f + erff(v * 0.70710678118f));
        G[m * 512 + n] = f2b_fast(v);
      }
    }
}

// ---------------- kernel 6: fc2 + residual, swapped roles (M=ch, N=tok) ----------------
__global__ __launch_bounds__(256) void k_fc2(const ushort* __restrict__ W2b,
                                             const ushort* __restrict__ G,
                                             const float* __restrict__ b2,
                                             const float* __restrict__ x,
                                             float* __restrict__ out) {
  f32x4 acc[4][4];
  gemm_core<8>(W2b + blockIdx.x * 128 * 512, 512, G + blockIdx.y * 128 * 512, 512, acc);
  const int lane = threadIdx.x & 63, wv = threadIdx.x >> 6;
  const int wr = (wv >> 1) * 64, wc = (wv & 1) * 64;
#pragma unroll
  for (int mt = 0; mt < 4; ++mt)
#pragma unroll
    for (int nt = 0; nt < 4; ++nt) {
      int t = blockIdx.y * 128 + wc + nt * 16 + (lane & 15);
      if (t < 20000) {
        int b = t / 10000, p = t - b * 10000;
#pragma unroll
        for (int r = 0; r < 4; ++r) {
          int c = blockIdx.x * 128 + wr + mt * 16 + (lane >> 4) * 4 + r;
          int idx = (b * 256 + c) * 10000 + p;
          out[idx] = x[idx] + acc[mt][nt][r] + b2[c];
        }
      }
    }
}

extern "C" void kernel_launch(void* const* d_in, const int* in_sizes, int n_in,
                              void* d_out, int out_size, void* d_ws, size_t ws_size,
                              hipStream_t stream) {
  const float* x     = (const float*)d_in[0];
  const float* wqkv  = (const float*)d_in[1];
  const float* wout  = (const float*)d_in[2];
  const float* bias  = (const float*)d_in[3];
  const float* gamma = (const float*)d_in[4];
  const float* beta  = (const float*)d_in[5];
  const float* w1    = (const float*)d_in[6];
  const float* b1    = (const float*)d_in[7];
  const float* w2    = (const float*)d_in[8];
  const float* b2    = (const float*)d_in[9];
  float* out = (float*)d_out;
  char* ws = (char*)d_ws;

  ushort* Xw    = (ushort*)(ws + 0);
  ushort* AO    = Xw;
  ushort* wqkvb = (ushort*)(ws + 10485760);
  ushort* woutb = (ushort*)(ws + 10878976);
  ushort* w1b   = (ushort*)(ws + 11010048);
  ushort* w2b   = (ushort*)(ws + 11272192);
  ushort* Qb    = (ushort*)(ws + 11534336);
  ushort* Kb    = (ushort*)(ws + 22020096);
  ushort* VbT   = (ushort*)(ws + 32505856);
  ushort* biasPh= (ushort*)(ws + 42991616);
  ushort* Yn    = (ushort*)(ws + 22020096);
  ushort* G     = (ushort*)(ws + 32505856);

  k_prep  <<<1152, 256, 0, stream>>>(x, wqkv, wout, w1, w2, bias,
                                     Xw, wqkvb, woutb, w1b, w2b, biasPh);
  k_qkv   <<<dim3(160, 6), 256, 0, stream>>>(Xw, wqkvb, Qb, Kb, VbT);
  k_attn  <<<1280, 256, 0, stream>>>(Qb, Kb, VbT, biasPh, AO);
  k_out_ln<<<320, 256, 0, stream>>>(AO, woutb, gamma, beta, Yn);
  k_fc1   <<<dim3(157, 4), 256, 0, stream>>>(Yn, w1b, b1, G);
  k_fc2   <<<dim3(2, 157), 256, 0, stream>>>(w2b, G, b2, x, out);
}